// Round 8
// baseline (1949.556 us; speedup 1.0000x reference)
//
#include <hip/hip_runtime.h>
#include <math.h>

// Problem constants
#define WIN   20
#define NWIN  399          // (4000-20)/10+1
#define NCH   2
#define TLEN  4000
#define NFR   798          // NCH*NWIN
#define KOPS  6
#define NB    2048
#define EPSV  1e-6f
#define RIDGE 1e-3f

// packed upper triangle index for 10x10, i<=j
#define TIX(i,j) ((i)*10 - (i)*((i)+1)/2 + (j))

// fast hardware transcendentals (~1e-7 rel err; output tolerance is 2.3e-2)
__device__ __forceinline__ float frcp(float x){float r;asm("v_rcp_f32 %0, %1":"=v"(r):"v"(x));return r;}
__device__ __forceinline__ float frsq(float x){float r;asm("v_rsq_f32 %0, %1":"=v"(r):"v"(x));return r;}
__device__ __forceinline__ float fsqr(float x){float r;asm("v_sqrt_f32 %0, %1":"=v"(r):"v"(x));return r;}

// ---------------------------------------------------------------- Jacobi 10x10
// Parallel-ordering (tournament) cyclic Jacobi: 9 rounds x 5 disjoint rotations.
// Disjoint Givens rotations commute; angles for a round are computed from the
// pre-round matrix (pivots/diagonals of distinct pairs don't interact), giving
// 5-way ILP on the rcp/sqrt chains — the latency bottleneck at <=2 waves/SIMD.
// A: packed upper triangle (55), V: row-major 10x10 (100). On exit diag(A)=evals,
// columns of V are eigenvectors: A_orig = V diag V^T.
// NOTE codegen: only launch from 64- or 256-thread blocks WITHOUT occupancy
// hints — 512-thread blocks trigger a 128-VGPR cap -> full scratch spill
// (rounds 5/6: VALUBusy 0.1%, 2x slowdown).
__device__ __forceinline__ void jacobi10(float* A, float* V) {
#pragma unroll
  for (int i = 0; i < 100; i++) V[i] = 0.f;
#pragma unroll
  for (int i = 0; i < 10; i++) V[i * 11] = 1.f;

  // round-robin tournament schedule for 10 indices (p<q), 9 rounds x 5 pairs
  constexpr int RP[9][5] = {
    {0,1,2,3,4}, {0,7,1,2,3}, {0,6,5,1,2}, {0,5,4,3,1}, {0,4,3,2,1},
    {0,3,2,1,8}, {0,2,1,6,7}, {0,1,4,5,6}, {0,2,3,4,5}};
  constexpr int RQ[9][5] = {
    {9,8,7,6,5}, {8,9,6,5,4}, {7,8,9,4,3}, {6,7,8,9,2}, {5,6,7,8,9},
    {4,5,6,7,9}, {3,4,5,9,8}, {2,3,9,8,7}, {1,9,8,7,6}};

  for (int sweep = 0; sweep < 7; ++sweep) {
    float off = 0.f, dia = 0.f;
#pragma unroll
    for (int p = 0; p < 10; p++) {
      float d = A[TIX(p, p)];
      dia = fmaf(d, d, dia);
#pragma unroll
      for (int q = p + 1; q < 10; q++) { float o = A[TIX(p, q)]; off = fmaf(o, o, off); }
    }
    float fro2 = dia + 2.f * off;
    if (__ballot(off > 1e-12f * fro2) == 0ull) break;
    float skipthr = 1e-13f * fro2;

#pragma unroll
    for (int r = 0; r < 9; r++) {
      // phase 1: 5 independent angle computations (ILP across transcendentals)
      float c5[5], s5[5], t5[5];
      bool d5[5];
#pragma unroll
      for (int k = 0; k < 5; k++) {
        const int p = RP[r][k], q = RQ[r][k];
        float apq = A[TIX(p, q)];
        d5[k] = (__ballot(apq * apq > skipthr) != 0ull);   // wave-uniform
        float app = A[TIX(p, p)];
        float aqq = A[TIX(q, q)];
        bool rot = fabsf(apq) > 1e-30f;
        float theta = (aqq - app) * frcp(rot ? 2.f * apq : 1.f);
        float t = copysignf(frcp(fabsf(theta) + fsqr(fmaf(theta, theta, 1.f))), theta);
        t = rot ? t : 0.f;                   // t=0 -> c=1, s=0: identity rotation
        float c = frsq(fmaf(t, t, 1.f));
        t5[k] = t; c5[k] = c; s5[k] = t * c;
      }
      // phase 2: apply rotations (disjoint pairs commute; sequential apply is
      // exactly J^T A J). Pivot/diag elements of pair k are untouched by k'!=k.
#pragma unroll
      for (int k = 0; k < 5; k++) {
        if (d5[k]) {                          // uniform branch
          const int p = RP[r][k], q = RQ[r][k];
          float c = c5[k], s = s5[k], t = t5[k];
          float apq = A[TIX(p, q)];
#pragma unroll
          for (int j = 0; j < 10; j++) {
            if (j == p || j == q) continue;
            const int jp = (j < p) ? TIX(j, p) : TIX(p, j);
            const int jq = (j < q) ? TIX(j, q) : TIX(q, j);
            float ajp = A[jp], ajq = A[jq];
            A[jp] = fmaf(c, ajp, -s * ajq);
            A[jq] = fmaf(s, ajp, c * ajq);
          }
          A[TIX(p, p)] = fmaf(-t, apq, A[TIX(p, p)]);
          A[TIX(q, q)] = fmaf(t, apq, A[TIX(q, q)]);
          A[TIX(p, q)] = 0.0f;
#pragma unroll
          for (int i = 0; i < 10; i++) {
            float vip = V[i * 10 + p], viq = V[i * 10 + q];
            V[i * 10 + p] = fmaf(c, vip, -s * viq);
            V[i * 10 + q] = fmaf(s, vip, c * viq);
          }
        }
      }
    }
  }
}

// ---------------------------------------------------------------- cov + stem
// hop-block decomposition: frame w = [b_w ; b_{w+1}] (10-blocks), w=0..398 per channel.
// C00 = T - b399 b399^T, C11 = T - b0 b0^T, C01 = Q, with
// T = sum_{i=0..399} b_i b_i^T, Q = sum_{i=0..398} b_i b_{i+1}^T (per channel).
__global__ __launch_bounds__(256) void k_cov_stem(const float* __restrict__ x,
                                                  const float* __restrict__ Wst,
                                                  float* __restrict__ Sout) {
  __shared__ float xl[NCH * TLEN];
  __shared__ float pT[2][NCH][100];   // [seg][ch][d*10+e]
  __shared__ float pQ[2][NCH][100];
  __shared__ float bsum[NCH][10];
  __shared__ float b0v[NCH][10];
  __shared__ float b399v[NCH][10];
  __shared__ float cov[400];
  __shared__ float wst[400];
  __shared__ float tmp[400];
  int b = blockIdx.x, tid = threadIdx.x;
  const float4* xg = (const float4*)(x + (size_t)b * NCH * TLEN);
  float4* xl4 = (float4*)xl;
  for (int i = tid; i < NCH * TLEN / 4; i += 256) xl4[i] = xg[i];
  for (int i = tid; i < 400; i += 256) wst[i] = Wst[i];
  __syncthreads();

  if (tid < 200) {
    int grp = tid / 100;               // 0 = T, 1 = Q
    int c = (tid % 100) / 50;
    int r = tid % 50;
    int seg = r / 25, tile = r % 25;
    int d0 = (tile / 5) * 2, e0 = (tile % 5) * 2;
    const float* xc = xl + c * TLEN;
    int i0 = seg * 200;
    int i1 = grp ? ((seg == 1) ? 399 : 200) : (i0 + 200);
    int eoff = grp ? 10 : 0;
    float a00 = 0.f, a01 = 0.f, a10 = 0.f, a11 = 0.f;
    for (int i = i0; i < i1; i++) {
      float2 bd = *(const float2*)(xc + i * 10 + d0);
      float2 be = *(const float2*)(xc + i * 10 + eoff + e0);
      a00 = fmaf(bd.x, be.x, a00); a01 = fmaf(bd.x, be.y, a01);
      a10 = fmaf(bd.y, be.x, a10); a11 = fmaf(bd.y, be.y, a11);
    }
    float* dst = grp ? &pQ[seg][c][0] : &pT[seg][c][0];
    dst[d0 * 10 + e0] = a00;
    dst[d0 * 10 + e0 + 1] = a01;
    dst[(d0 + 1) * 10 + e0] = a10;
    dst[(d0 + 1) * 10 + e0 + 1] = a11;
  } else if (tid >= 200 && tid < 220) {
    int c = (tid - 200) / 10, d = (tid - 200) % 10;
    const float* xc = xl + c * TLEN;
    float s = 0.f;
    for (int i = 0; i < 400; i++) s += xc[i * 10 + d];
    bsum[c][d] = s;
    b0v[c][d] = xc[d];
    b399v[c][d] = xc[3990 + d];
  }
  __syncthreads();

  const float invN = 1.0f / (float)NFR;
  const float invN1 = 1.0f / (float)(NFR - 1);
  for (int o = tid; o < 400; o += 256) {
    int d = o / 20, e = o % 20;
    int dl = d % 10, el = e % 10;
    float s2;
    if (d < 10 && e < 10)
      s2 = (pT[0][0][dl * 10 + el] + pT[1][0][dl * 10 + el] - b399v[0][dl] * b399v[0][el]) +
           (pT[0][1][dl * 10 + el] + pT[1][1][dl * 10 + el] - b399v[1][dl] * b399v[1][el]);
    else if (d >= 10 && e >= 10)
      s2 = (pT[0][0][dl * 10 + el] + pT[1][0][dl * 10 + el] - b0v[0][dl] * b0v[0][el]) +
           (pT[0][1][dl * 10 + el] + pT[1][1][dl * 10 + el] - b0v[1][dl] * b0v[1][el]);
    else if (d < 10)
      s2 = pQ[0][0][dl * 10 + el] + pQ[1][0][dl * 10 + el] +
           pQ[0][1][dl * 10 + el] + pQ[1][1][dl * 10 + el];
    else
      s2 = pQ[0][0][el * 10 + dl] + pQ[1][0][el * 10 + dl] +
           pQ[0][1][el * 10 + dl] + pQ[1][1][el * 10 + dl];
    float md = (d < 10) ? (bsum[0][dl] - b399v[0][dl] + bsum[1][dl] - b399v[1][dl])
                        : (bsum[0][dl] - b0v[0][dl] + bsum[1][dl] - b0v[1][dl]);
    float me = (e < 10) ? (bsum[0][el] - b399v[0][el] + bsum[1][el] - b399v[1][el])
                        : (bsum[0][el] - b0v[0][el] + bsum[1][el] - b0v[1][el]);
    float v = (s2 - (float)NFR * (md * invN) * (me * invN)) * invN1;
    if (d == e) v += RIDGE;
    cov[o] = v;
  }
  __syncthreads();
  for (int o = tid; o < 400; o += 256) {
    int j = o / 20, l = o % 20;
    float acc = 0.f;
    for (int k2 = 0; k2 < 20; k2++) acc = fmaf(cov[j * 20 + k2], wst[k2 * 20 + l], acc);
    tmp[o] = acc;
  }
  __syncthreads();
  for (int o = tid; o < 400; o += 256) {
    int i = o / 20, l = o % 20;
    float acc = 0.f;
    for (int j = 0; j < 20; j++) acc = fmaf(wst[j * 20 + i], tmp[j * 20 + l], acc);
    if (i == l) acc += RIDGE;
    Sout[b * 400 + o] = acc;
  }
}

// ---------------------------------------------------------------- cand = W^T S W + ridge I (cell 0 only, DIN=20)
__global__ __launch_bounds__(256) void k_cand20(const float* __restrict__ Sin,
                                                const float* __restrict__ Wop,
                                                float* __restrict__ cand, int BC) {
  const int DIN = 20;
  __shared__ float Sl[DIN * DIN];
  __shared__ float Wl[12 * DIN * 10];
  __shared__ float Tl[12 * DIN * 10];
  int bc = blockIdx.x, tid = threadIdx.x;
  for (int i = tid; i < DIN * DIN; i += 256) Sl[i] = Sin[bc * DIN * DIN + i];
  for (int i = tid; i < 12 * DIN * 10; i += 256) Wl[i] = Wop[i];
  __syncthreads();
  for (int o = tid; o < 12 * DIN * 10; o += 256) {
    int mk = o / (DIN * 10);
    int r = o % (DIN * 10);
    int j = r / 10, n = r % 10;
    float acc = 0.f;
    for (int l = 0; l < DIN; l++) acc = fmaf(Sl[j * DIN + l], Wl[mk * DIN * 10 + l * 10 + n], acc);
    Tl[o] = acc;
  }
  __syncthreads();
  int NM = 12 * BC;
  for (int o = tid; o < 12 * 55; o += 256) {
    int mk = o / 55, t = o % 55;
    int t0 = t, i = 0;
    while (t0 >= 10 - i) { t0 -= 10 - i; i++; }
    int n = i + t0;
    float acc = 0.f;
    for (int j = 0; j < DIN; j++)
      acc = fmaf(Wl[mk * DIN * 10 + j * 10 + i], Tl[mk * DIN * 10 + j * 10 + n], acc);
    if (i == n) acc += RIDGE;
    cand[t * NM + mk * BC + bc] = acc;
  }
}

// ---------------------------------------------------------------- shared logm epilogue
__device__ __forceinline__ void logm_epilogue(float* A, float* V,
                                              float* __restrict__ cand, int NM, int mat) {
  float f[10];
#pragma unroll
  for (int r = 0; r < 10; r++) f[r] = __logf(fmaxf(A[TIX(r, r)], EPSV));
#pragma unroll
  for (int i = 0; i < 10; i++) {
    float w[10];
#pragma unroll
    for (int r = 0; r < 10; r++) w[r] = V[i * 10 + r] * f[r];
#pragma unroll
    for (int n = i; n < 10; n++) {
      float acc = 0.f;
#pragma unroll
      for (int r = 0; r < 10; r++) acc = fmaf(w[r], V[n * 10 + r], acc);
      cand[TIX(i, n) * NM + mat] = acc;
    }
  }
}

// ---------------------------------------------------------------- logm from cand buffer (cell 0)
__global__ __launch_bounds__(256) void k_logm(float* __restrict__ cand, int NM) {
  int mat = blockIdx.x * 256 + threadIdx.x;   // NM is a multiple of 256
  float A[55];
#pragma unroll
  for (int t = 0; t < 55; t++) A[t] = cand[t * NM + mat];
  float V[100];
  jacobi10(A, V);
  logm_epilogue(A, V, cand, NM, mat);
}

// ---------------------------------------------------------------- fused cand+logm (cells 1,2; DIN=10)
// S is element-major [e][BC] (written by k_expm) -> fully coalesced reads.
// W read straight from global with a wave-uniform mk (scalar loads, L2-hot).
template <int BC>
__global__ __launch_bounds__(256) void k_candlogm(const float* __restrict__ Sin,
                                                  const float* __restrict__ Wop,
                                                  float* __restrict__ cand) {
  const int NM = 12 * BC;
  int tid = threadIdx.x;
  int mat = blockIdx.x * 256 + tid;
  int mk = __builtin_amdgcn_readfirstlane(mat / BC);   // 256 | BC -> uniform
  int bc = mat % BC;
  const float* Wm = Wop + mk * 100;
  const float* Sb = Sin + bc;            // elem-major: S[e*BC + bc]

  float U[100];
#pragma unroll
  for (int i = 0; i < 100; i++) U[i] = 0.f;
#pragma unroll
  for (int j = 0; j < 10; j++) {
    float sr[10];
#pragma unroll
    for (int l = 0; l < 10; l++) sr[l] = Sb[(j * 10 + l) * BC];
    float wr[10];
#pragma unroll
    for (int i = 0; i < 10; i++) wr[i] = Wm[j * 10 + i];
#pragma unroll
    for (int i = 0; i < 10; i++)
#pragma unroll
      for (int l = 0; l < 10; l++) U[i * 10 + l] = fmaf(wr[i], sr[l], U[i * 10 + l]);
  }
  float A[55];
#pragma unroll
  for (int t = 0; t < 55; t++) A[t] = 0.f;
#pragma unroll
  for (int i = 0; i < 10; i++) A[TIX(i, i)] = RIDGE;
#pragma unroll
  for (int l = 0; l < 10; l++) {
    float wr[10];
#pragma unroll
    for (int n = 0; n < 10; n++) wr[n] = Wm[l * 10 + n];
#pragma unroll
    for (int i = 0; i < 10; i++) {
      float u = U[i * 10 + l];
#pragma unroll
      for (int n = i; n < 10; n++) A[TIX(i, n)] = fmaf(u, wr[n], A[TIX(i, n)]);
    }
  }
  float V[100];
  jacobi10(A, V);
  logm_epilogue(A, V, cand, NM, mat);
}

// ---------------------------------------------------------------- sparsemax (per-thread, K=6)
__device__ __forceinline__ void sparsemax6(const float* __restrict__ a, int row, float* w) {
  float z[KOPS], zs[KOPS];
#pragma unroll
  for (int i = 0; i < KOPS; i++) { z[i] = a[row * KOPS + i]; zs[i] = z[i]; }
#pragma unroll
  for (int i = 0; i < KOPS; i++)
#pragma unroll
    for (int j = i + 1; j < KOPS; j++)
      if (zs[j] > zs[i]) { float tm = zs[i]; zs[i] = zs[j]; zs[j] = tm; }
  float acc = 0.f, zcp = 1.f; float cnt = 1.f;
#pragma unroll
  for (int i = 0; i < KOPS; i++) {
    acc += zs[i];
    if (1.0f + (float)(i + 1) * zs[i] > acc) { cnt = (float)(i + 1); zcp = acc; }
  }
  float tau = (zcp - 1.0f) / cnt;
#pragma unroll
  for (int i = 0; i < KOPS; i++) w[i] = fmaxf(z[i] - tau, 0.0f);
}

// ---------------------------------------------------------------- expm of weighted sum -> new S
// Output element-major [e][2*BC] -> fully coalesced stores, coalesced reads downstream.
template <int BC, int C>
__global__ __launch_bounds__(64) void k_expm(const float* __restrict__ L,
                                             const float* __restrict__ alphas, int row,
                                             float* __restrict__ Sout) {
  const int NM = 12 * BC;
  const int NE = 2 * BC;
  int id = blockIdx.x * 64 + threadIdx.x;  // id = m*BC + bc; 2*BC is a multiple of 64
  int m = id / BC;
  int bc = id % BC;
  float w[KOPS];
  sparsemax6(alphas, row, w);
  float A[55];
#pragma unroll
  for (int t = 0; t < 55; t++) {
    float acc = 0.f;
#pragma unroll
    for (int k2 = 0; k2 < KOPS; k2++) acc = fmaf(w[k2], L[t * NM + (m * KOPS + k2) * BC + bc], acc);
    A[t] = acc;
  }
  float V[100];
  jacobi10(A, V);
  float f[10];
#pragma unroll
  for (int r = 0; r < 10; r++) f[r] = __expf(A[TIX(r, r)]);
  int b = bc / C, c = bc % C;
  int idm = b * 2 * C + m * C + c;         // next stage's bc index
  float* out = Sout + idm;
#pragma unroll
  for (int i = 0; i < 10; i++) {
    float wv[10];
#pragma unroll
    for (int r = 0; r < 10; r++) wv[r] = V[i * 10 + r] * f[r];
#pragma unroll
    for (int n = i; n < 10; n++) {
      float acc = 0.f;
#pragma unroll
      for (int r = 0; r < 10; r++) acc = fmaf(wv[r], V[n * 10 + r], acc);
      out[(i * 10 + n) * NE] = acc;
      if (n != i) out[(n * 10 + i) * NE] = acc;
    }
  }
}

// ---------------------------------------------------------------- final logm + classifier (fused)
// S elem-major [e][16384]. Each thread: logm of one (b,ch) matrix, classifier
// partials acc[10], shfl-reduce over the 8 ch lanes, lane ch==0 stores.
__global__ __launch_bounds__(64) void k_final(const float* __restrict__ Sin,
                                              const float* __restrict__ Wc,
                                              const float* __restrict__ bcv,
                                              float* __restrict__ out) {
  const int NE = 8 * NB;
  int id = blockIdx.x * 64 + threadIdx.x;  // b*8+ch, total 16384
  int ch = id & 7;
  float A[55];
#pragma unroll
  for (int i = 0; i < 10; i++)
#pragma unroll
    for (int n = i; n < 10; n++) A[TIX(i, n)] = Sin[(i * 10 + n) * NE + id];
  float V[100];
  jacobi10(A, V);
  float f[10];
#pragma unroll
  for (int r = 0; r < 10; r++) f[r] = __logf(fmaxf(A[TIX(r, r)], EPSV));
  float acc[10];
#pragma unroll
  for (int c2 = 0; c2 < 10; c2++) acc[c2] = 0.f;
  const float* wbase = Wc + ch * 1000;     // row (ch*100 + i*10 + n), 10 cols
#pragma unroll
  for (int i = 0; i < 10; i++) {
    float wv[10];
#pragma unroll
    for (int r = 0; r < 10; r++) wv[r] = V[i * 10 + r] * f[r];
#pragma unroll
    for (int n = 0; n < 10; n++) {
      float lv = 0.f;
#pragma unroll
      for (int r = 0; r < 10; r++) lv = fmaf(wv[r], V[n * 10 + r], lv);
      const float* wrow = wbase + (i * 10 + n) * 10;
#pragma unroll
      for (int h = 0; h < 5; h++) {
        float2 wc2 = *(const float2*)(wrow + 2 * h);
        acc[2 * h]     = fmaf(lv, wc2.x, acc[2 * h]);
        acc[2 * h + 1] = fmaf(lv, wc2.y, acc[2 * h + 1]);
      }
    }
  }
  // reduce over the 8 channel lanes (lanes id&7 within each group of 8)
#pragma unroll
  for (int mk = 1; mk < 8; mk <<= 1) {
#pragma unroll
    for (int c2 = 0; c2 < 10; c2++) acc[c2] += __shfl_xor(acc[c2], mk, 8);
  }
  if (ch == 0) {
    int b = id >> 3;
#pragma unroll
    for (int c2 = 0; c2 < 10; c2++) out[b * 10 + c2] = acc[c2] + bcv[c2];
  }
}

// ---------------------------------------------------------------- launch
extern "C" void kernel_launch(void* const* d_in, const int* in_sizes, int n_in,
                              void* d_out, int out_size, void* d_ws, size_t ws_size,
                              hipStream_t stream) {
  const float* x      = (const float*)d_in[0];
  const float* Wst    = (const float*)d_in[1];
  const float* Wop0   = (const float*)d_in[2];
  const float* Wop1   = (const float*)d_in[3];
  const float* Wop2   = (const float*)d_in[4];
  const float* alphas = (const float*)d_in[5];
  const float* Wcls   = (const float*)d_in[6];
  const float* bcls   = (const float*)d_in[7];
  float* out = (float*)d_out;

  // workspace layout (floats): Sa(2048*800) | Sb(2048*800) | cand(55*12*2048*4)
  float* ws   = (float*)d_ws;
  float* Sa   = ws;
  float* Sb   = Sa + (size_t)NB * 800;
  float* cand = Sb + (size_t)NB * 800;

  k_cov_stem<<<NB, 256, 0, stream>>>(x, Wst, Sa);

  // cell 0: S (B,1,20,20) -> (B,2,10,10)   (DIN=20: split cand/logm path)
  k_cand20<<<NB, 256, 0, stream>>>(Sa, Wop0, cand, NB);
  k_logm<<<(12 * NB) / 256, 256, 0, stream>>>(cand, 12 * NB);
  k_expm<NB, 1><<<(2 * NB) / 64, 64, 0, stream>>>(cand, alphas, 0, Sb);

  // cell 1: (B,2,10,10) -> (B,4,10,10)   (fused cand+logm, elem-major S)
  k_candlogm<NB * 2><<<(12 * NB * 2) / 256, 256, 0, stream>>>(Sb, Wop1, cand);
  k_expm<NB * 2, 2><<<(4 * NB) / 64, 64, 0, stream>>>(cand, alphas, 1, Sa);

  // cell 2: (B,4,10,10) -> (B,8,10,10)
  k_candlogm<NB * 4><<<(12 * NB * 4) / 256, 256, 0, stream>>>(Sa, Wop2, cand);
  k_expm<NB * 4, 4><<<(8 * NB) / 64, 64, 0, stream>>>(cand, alphas, 2, Sb);

  // final logm + classifier (fused)
  k_final<<<(8 * NB) / 64, 64, 0, stream>>>(Sb, Wcls, bcls, out);
}

// Round 9
// 1835.634 us; speedup vs baseline: 1.0621x; 1.0621x over previous
//
#include <hip/hip_runtime.h>
#include <math.h>

// Problem constants
#define WIN   20
#define NWIN  399          // (4000-20)/10+1
#define NCH   2
#define TLEN  4000
#define NFR   798          // NCH*NWIN
#define KOPS  6
#define NB    2048
#define EPSV  1e-6f
#define RIDGE 1e-3f

// packed upper triangle index for 10x10, i<=j
#define TIX(i,j) ((i)*10 - (i)*((i)+1)/2 + (j))

// fast hardware transcendentals (~1e-7 rel err; output tolerance is 2.3e-2)
__device__ __forceinline__ float frcp(float x){float r;asm("v_rcp_f32 %0, %1":"=v"(r):"v"(x));return r;}
__device__ __forceinline__ float frsq(float x){float r;asm("v_rsq_f32 %0, %1":"=v"(r):"v"(x));return r;}
__device__ __forceinline__ float fsqr(float x){float r;asm("v_sqrt_f32 %0, %1":"=v"(r):"v"(x));return r;}

// ---------------------------------------------------------------- Jacobi 10x10
// Tournament-ordered cyclic Jacobi, 9 rounds x 5 disjoint rotations per sweep.
// Phase 1 computes all 5 angles of a round from the pre-round matrix (disjoint
// pairs -> angles stay exact under sequential apply); the 5 rcp/sqrt/rsq chains
// are independent -> 5-way ILP on the latency bottleneck. Phase 2 applies all 5
// rotations unconditionally (straight-line, no ballots/branches — round 8's
// branchy version spilled: VGPR 216 + 26MB scratch writes).
// A: packed upper triangle (55), V: row-major 10x10 (100). On exit diag(A)=evals,
// columns of V are eigenvectors: A_orig = V diag V^T.
// NOTE codegen: only launch from 64- or 256-thread blocks WITHOUT occupancy
// hints — 512-thread blocks trigger a 128-VGPR cap -> full scratch spill
// (rounds 5/6: VALUBusy 0.1%, 2x slowdown). VGPR occupancy steps only at
// 64/128/256 (m69), so 129..256 VGPR all give 2 waves/SIMD — ILP is the only
// latency lever here.
__device__ __forceinline__ void jacobi10(float* A, float* V) {
#pragma unroll
  for (int i = 0; i < 100; i++) V[i] = 0.f;
#pragma unroll
  for (int i = 0; i < 10; i++) V[i * 11] = 1.f;

  // round-robin tournament schedule for 10 indices (p<q), 9 rounds x 5 pairs
  constexpr int RP[9][5] = {
    {0,1,2,3,4}, {0,7,1,2,3}, {0,6,5,1,2}, {0,5,4,3,1}, {0,4,3,2,1},
    {0,3,2,1,8}, {0,2,1,6,7}, {0,1,4,5,6}, {0,2,3,4,5}};
  constexpr int RQ[9][5] = {
    {9,8,7,6,5}, {8,9,6,5,4}, {7,8,9,4,3}, {6,7,8,9,2}, {5,6,7,8,9},
    {4,5,6,7,9}, {3,4,5,9,8}, {2,3,9,8,7}, {1,9,8,7,6}};

  for (int sweep = 0; sweep < 7; ++sweep) {
    float off = 0.f, dia = 0.f;
#pragma unroll
    for (int p = 0; p < 10; p++) {
      float d = A[TIX(p, p)];
      dia = fmaf(d, d, dia);
#pragma unroll
      for (int q = p + 1; q < 10; q++) { float o = A[TIX(p, q)]; off = fmaf(o, o, off); }
    }
    if (__ballot(off > 1e-12f * (dia + 2.f * off)) == 0ull) break;

#pragma unroll
    for (int r = 0; r < 9; r++) {
      // phase 1: 5 independent angle computations (ILP across transcendentals)
      float c5[5], s5[5], t5[5];
#pragma unroll
      for (int k = 0; k < 5; k++) {
        const int p = RP[r][k], q = RQ[r][k];
        float apq = A[TIX(p, q)];
        float app = A[TIX(p, p)];
        float aqq = A[TIX(q, q)];
        bool rot = fabsf(apq) > 1e-30f;
        float theta = (aqq - app) * frcp(rot ? 2.f * apq : 1.f);
        float t = copysignf(frcp(fabsf(theta) + fsqr(fmaf(theta, theta, 1.f))), theta);
        t = rot ? t : 0.f;                   // t=0 -> c=1, s=0: identity rotation
        t5[k] = t;
        c5[k] = frsq(fmaf(t, t, 1.f));
        s5[k] = t * c5[k];
      }
      // phase 2: apply all 5 rotations, straight-line (disjoint pairs commute;
      // pivot/diag elements of pair k are untouched by k'!=k).
#pragma unroll
      for (int k = 0; k < 5; k++) {
        const int p = RP[r][k], q = RQ[r][k];
        float c = c5[k], s = s5[k], t = t5[k];
        float apq = A[TIX(p, q)];
#pragma unroll
        for (int j = 0; j < 10; j++) {
          if (j == p || j == q) continue;
          const int jp = (j < p) ? TIX(j, p) : TIX(p, j);
          const int jq = (j < q) ? TIX(j, q) : TIX(q, j);
          float ajp = A[jp], ajq = A[jq];
          A[jp] = fmaf(c, ajp, -s * ajq);
          A[jq] = fmaf(s, ajp, c * ajq);
        }
        A[TIX(p, p)] = fmaf(-t, apq, A[TIX(p, p)]);
        A[TIX(q, q)] = fmaf(t, apq, A[TIX(q, q)]);
        A[TIX(p, q)] = 0.0f;
#pragma unroll
        for (int i = 0; i < 10; i++) {
          float vip = V[i * 10 + p], viq = V[i * 10 + q];
          V[i * 10 + p] = fmaf(c, vip, -s * viq);
          V[i * 10 + q] = fmaf(s, vip, c * viq);
        }
      }
    }
  }
}

// ---------------------------------------------------------------- cov + stem
// hop-block decomposition: frame w = [b_w ; b_{w+1}] (10-blocks), w=0..398 per channel.
// C00 = T - b399 b399^T, C11 = T - b0 b0^T, C01 = Q, with
// T = sum_{i=0..399} b_i b_i^T, Q = sum_{i=0..398} b_i b_{i+1}^T (per channel).
__global__ __launch_bounds__(256) void k_cov_stem(const float* __restrict__ x,
                                                  const float* __restrict__ Wst,
                                                  float* __restrict__ Sout) {
  __shared__ float xl[NCH * TLEN];
  __shared__ float pT[2][NCH][100];   // [seg][ch][d*10+e]
  __shared__ float pQ[2][NCH][100];
  __shared__ float bsum[NCH][10];
  __shared__ float b0v[NCH][10];
  __shared__ float b399v[NCH][10];
  __shared__ float cov[400];
  __shared__ float wst[400];
  __shared__ float tmp[400];
  int b = blockIdx.x, tid = threadIdx.x;
  const float4* xg = (const float4*)(x + (size_t)b * NCH * TLEN);
  float4* xl4 = (float4*)xl;
  for (int i = tid; i < NCH * TLEN / 4; i += 256) xl4[i] = xg[i];
  for (int i = tid; i < 400; i += 256) wst[i] = Wst[i];
  __syncthreads();

  if (tid < 200) {
    int grp = tid / 100;               // 0 = T, 1 = Q
    int c = (tid % 100) / 50;
    int r = tid % 50;
    int seg = r / 25, tile = r % 25;
    int d0 = (tile / 5) * 2, e0 = (tile % 5) * 2;
    const float* xc = xl + c * TLEN;
    int i0 = seg * 200;
    int i1 = grp ? ((seg == 1) ? 399 : 200) : (i0 + 200);
    int eoff = grp ? 10 : 0;
    float a00 = 0.f, a01 = 0.f, a10 = 0.f, a11 = 0.f;
    for (int i = i0; i < i1; i++) {
      float2 bd = *(const float2*)(xc + i * 10 + d0);
      float2 be = *(const float2*)(xc + i * 10 + eoff + e0);
      a00 = fmaf(bd.x, be.x, a00); a01 = fmaf(bd.x, be.y, a01);
      a10 = fmaf(bd.y, be.x, a10); a11 = fmaf(bd.y, be.y, a11);
    }
    float* dst = grp ? &pQ[seg][c][0] : &pT[seg][c][0];
    dst[d0 * 10 + e0] = a00;
    dst[d0 * 10 + e0 + 1] = a01;
    dst[(d0 + 1) * 10 + e0] = a10;
    dst[(d0 + 1) * 10 + e0 + 1] = a11;
  } else if (tid >= 200 && tid < 220) {
    int c = (tid - 200) / 10, d = (tid - 200) % 10;
    const float* xc = xl + c * TLEN;
    float s = 0.f;
    for (int i = 0; i < 400; i++) s += xc[i * 10 + d];
    bsum[c][d] = s;
    b0v[c][d] = xc[d];
    b399v[c][d] = xc[3990 + d];
  }
  __syncthreads();

  const float invN = 1.0f / (float)NFR;
  const float invN1 = 1.0f / (float)(NFR - 1);
  for (int o = tid; o < 400; o += 256) {
    int d = o / 20, e = o % 20;
    int dl = d % 10, el = e % 10;
    float s2;
    if (d < 10 && e < 10)
      s2 = (pT[0][0][dl * 10 + el] + pT[1][0][dl * 10 + el] - b399v[0][dl] * b399v[0][el]) +
           (pT[0][1][dl * 10 + el] + pT[1][1][dl * 10 + el] - b399v[1][dl] * b399v[1][el]);
    else if (d >= 10 && e >= 10)
      s2 = (pT[0][0][dl * 10 + el] + pT[1][0][dl * 10 + el] - b0v[0][dl] * b0v[0][el]) +
           (pT[0][1][dl * 10 + el] + pT[1][1][dl * 10 + el] - b0v[1][dl] * b0v[1][el]);
    else if (d < 10)
      s2 = pQ[0][0][dl * 10 + el] + pQ[1][0][dl * 10 + el] +
           pQ[0][1][dl * 10 + el] + pQ[1][1][dl * 10 + el];
    else
      s2 = pQ[0][0][el * 10 + dl] + pQ[1][0][el * 10 + dl] +
           pQ[0][1][el * 10 + dl] + pQ[1][1][el * 10 + dl];
    float md = (d < 10) ? (bsum[0][dl] - b399v[0][dl] + bsum[1][dl] - b399v[1][dl])
                        : (bsum[0][dl] - b0v[0][dl] + bsum[1][dl] - b0v[1][dl]);
    float me = (e < 10) ? (bsum[0][el] - b399v[0][el] + bsum[1][el] - b399v[1][el])
                        : (bsum[0][el] - b0v[0][el] + bsum[1][el] - b0v[1][el]);
    float v = (s2 - (float)NFR * (md * invN) * (me * invN)) * invN1;
    if (d == e) v += RIDGE;
    cov[o] = v;
  }
  __syncthreads();
  for (int o = tid; o < 400; o += 256) {
    int j = o / 20, l = o % 20;
    float acc = 0.f;
    for (int k2 = 0; k2 < 20; k2++) acc = fmaf(cov[j * 20 + k2], wst[k2 * 20 + l], acc);
    tmp[o] = acc;
  }
  __syncthreads();
  for (int o = tid; o < 400; o += 256) {
    int i = o / 20, l = o % 20;
    float acc = 0.f;
    for (int j = 0; j < 20; j++) acc = fmaf(wst[j * 20 + i], tmp[j * 20 + l], acc);
    if (i == l) acc += RIDGE;
    Sout[b * 400 + o] = acc;
  }
}

// ---------------------------------------------------------------- cand = W^T S W + ridge I (cell 0 only, DIN=20)
__global__ __launch_bounds__(256) void k_cand20(const float* __restrict__ Sin,
                                                const float* __restrict__ Wop,
                                                float* __restrict__ cand, int BC) {
  const int DIN = 20;
  __shared__ float Sl[DIN * DIN];
  __shared__ float Wl[12 * DIN * 10];
  __shared__ float Tl[12 * DIN * 10];
  int bc = blockIdx.x, tid = threadIdx.x;
  for (int i = tid; i < DIN * DIN; i += 256) Sl[i] = Sin[bc * DIN * DIN + i];
  for (int i = tid; i < 12 * DIN * 10; i += 256) Wl[i] = Wop[i];
  __syncthreads();
  for (int o = tid; o < 12 * DIN * 10; o += 256) {
    int mk = o / (DIN * 10);
    int r = o % (DIN * 10);
    int j = r / 10, n = r % 10;
    float acc = 0.f;
    for (int l = 0; l < DIN; l++) acc = fmaf(Sl[j * DIN + l], Wl[mk * DIN * 10 + l * 10 + n], acc);
    Tl[o] = acc;
  }
  __syncthreads();
  int NM = 12 * BC;
  for (int o = tid; o < 12 * 55; o += 256) {
    int mk = o / 55, t = o % 55;
    int t0 = t, i = 0;
    while (t0 >= 10 - i) { t0 -= 10 - i; i++; }
    int n = i + t0;
    float acc = 0.f;
    for (int j = 0; j < DIN; j++)
      acc = fmaf(Wl[mk * DIN * 10 + j * 10 + i], Tl[mk * DIN * 10 + j * 10 + n], acc);
    if (i == n) acc += RIDGE;
    cand[t * NM + mk * BC + bc] = acc;
  }
}

// ---------------------------------------------------------------- shared logm epilogue
__device__ __forceinline__ void logm_epilogue(float* A, float* V,
                                              float* __restrict__ cand, int NM, int mat) {
  float f[10];
#pragma unroll
  for (int r = 0; r < 10; r++) f[r] = __logf(fmaxf(A[TIX(r, r)], EPSV));
#pragma unroll
  for (int i = 0; i < 10; i++) {
    float w[10];
#pragma unroll
    for (int r = 0; r < 10; r++) w[r] = V[i * 10 + r] * f[r];
#pragma unroll
    for (int n = i; n < 10; n++) {
      float acc = 0.f;
#pragma unroll
      for (int r = 0; r < 10; r++) acc = fmaf(w[r], V[n * 10 + r], acc);
      cand[TIX(i, n) * NM + mat] = acc;
    }
  }
}

// ---------------------------------------------------------------- logm from cand buffer (cell 0)
__global__ __launch_bounds__(256) void k_logm(float* __restrict__ cand, int NM) {
  int mat = blockIdx.x * 256 + threadIdx.x;   // NM is a multiple of 256
  float A[55];
#pragma unroll
  for (int t = 0; t < 55; t++) A[t] = cand[t * NM + mat];
  float V[100];
  jacobi10(A, V);
  logm_epilogue(A, V, cand, NM, mat);
}

// ---------------------------------------------------------------- fused cand+logm (cells 1,2; DIN=10)
// S is element-major [e][BC] (written by k_expm) -> fully coalesced reads.
template <int BC>
__global__ __launch_bounds__(256) void k_candlogm(const float* __restrict__ Sin,
                                                  const float* __restrict__ Wop,
                                                  float* __restrict__ cand) {
  __shared__ float Wl[1200];
  int tid = threadIdx.x;
  for (int i = tid; i < 1200; i += 256) Wl[i] = Wop[i];
  __syncthreads();
  const int NM = 12 * BC;
  int mat = blockIdx.x * 256 + tid;
  int mk = mat / BC, bc = mat % BC;      // 256 | BC, so mk uniform per block
  const float* Wm = Wl + mk * 100;
  const float* Sb = Sin + bc;            // elem-major: S[e*BC + bc]

  float U[100];
#pragma unroll
  for (int i = 0; i < 100; i++) U[i] = 0.f;
#pragma unroll
  for (int j = 0; j < 10; j++) {
    float sr[10];
#pragma unroll
    for (int l = 0; l < 10; l++) sr[l] = Sb[(j * 10 + l) * BC];
    float wr[10];
#pragma unroll
    for (int i = 0; i < 10; i++) wr[i] = Wm[j * 10 + i];
#pragma unroll
    for (int i = 0; i < 10; i++)
#pragma unroll
      for (int l = 0; l < 10; l++) U[i * 10 + l] = fmaf(wr[i], sr[l], U[i * 10 + l]);
  }
  float A[55];
#pragma unroll
  for (int t = 0; t < 55; t++) A[t] = 0.f;
#pragma unroll
  for (int i = 0; i < 10; i++) A[TIX(i, i)] = RIDGE;
#pragma unroll
  for (int l = 0; l < 10; l++) {
    float wr[10];
#pragma unroll
    for (int n = 0; n < 10; n++) wr[n] = Wm[l * 10 + n];
#pragma unroll
    for (int i = 0; i < 10; i++) {
      float u = U[i * 10 + l];
#pragma unroll
      for (int n = i; n < 10; n++) A[TIX(i, n)] = fmaf(u, wr[n], A[TIX(i, n)]);
    }
  }
  float V[100];
  jacobi10(A, V);
  logm_epilogue(A, V, cand, NM, mat);
}

// ---------------------------------------------------------------- sparsemax (per-thread, K=6)
__device__ __forceinline__ void sparsemax6(const float* __restrict__ a, int row, float* w) {
  float z[KOPS], zs[KOPS];
#pragma unroll
  for (int i = 0; i < KOPS; i++) { z[i] = a[row * KOPS + i]; zs[i] = z[i]; }
#pragma unroll
  for (int i = 0; i < KOPS; i++)
#pragma unroll
    for (int j = i + 1; j < KOPS; j++)
      if (zs[j] > zs[i]) { float tm = zs[i]; zs[i] = zs[j]; zs[j] = tm; }
  float acc = 0.f, zcp = 1.f; float cnt = 1.f;
#pragma unroll
  for (int i = 0; i < KOPS; i++) {
    acc += zs[i];
    if (1.0f + (float)(i + 1) * zs[i] > acc) { cnt = (float)(i + 1); zcp = acc; }
  }
  float tau = (zcp - 1.0f) / cnt;
#pragma unroll
  for (int i = 0; i < KOPS; i++) w[i] = fmaxf(z[i] - tau, 0.0f);
}

// ---------------------------------------------------------------- expm of weighted sum -> new S
// Output element-major [e][2*BC] -> fully coalesced stores, coalesced reads downstream.
template <int BC, int C>
__global__ __launch_bounds__(64) void k_expm(const float* __restrict__ L,
                                             const float* __restrict__ alphas, int row,
                                             float* __restrict__ Sout) {
  const int NM = 12 * BC;
  const int NE = 2 * BC;
  int id = blockIdx.x * 64 + threadIdx.x;  // id = m*BC + bc; 2*BC is a multiple of 64
  int m = id / BC;
  int bc = id % BC;
  float w[KOPS];
  sparsemax6(alphas, row, w);
  float A[55];
#pragma unroll
  for (int t = 0; t < 55; t++) {
    float acc = 0.f;
#pragma unroll
    for (int k2 = 0; k2 < KOPS; k2++) acc = fmaf(w[k2], L[t * NM + (m * KOPS + k2) * BC + bc], acc);
    A[t] = acc;
  }
  float V[100];
  jacobi10(A, V);
  float f[10];
#pragma unroll
  for (int r = 0; r < 10; r++) f[r] = __expf(A[TIX(r, r)]);
  int b = bc / C, c = bc % C;
  int idm = b * 2 * C + m * C + c;         // next stage's bc index
  float* out = Sout + idm;
#pragma unroll
  for (int i = 0; i < 10; i++) {
    float wv[10];
#pragma unroll
    for (int r = 0; r < 10; r++) wv[r] = V[i * 10 + r] * f[r];
#pragma unroll
    for (int n = i; n < 10; n++) {
      float acc = 0.f;
#pragma unroll
      for (int r = 0; r < 10; r++) acc = fmaf(wv[r], V[n * 10 + r], acc);
      out[(i * 10 + n) * NE] = acc;
      if (n != i) out[(n * 10 + i) * NE] = acc;
    }
  }
}

// ---------------------------------------------------------------- final logm + classifier (fused)
// S elem-major [e][16384]. Each thread: logm of one (b,ch) matrix, classifier
// partials acc[10], shfl-reduce over the 8 ch lanes, lane ch==0 stores.
__global__ __launch_bounds__(64) void k_final(const float* __restrict__ Sin,
                                              const float* __restrict__ Wc,
                                              const float* __restrict__ bcv,
                                              float* __restrict__ out) {
  const int NE = 8 * NB;
  int id = blockIdx.x * 64 + threadIdx.x;  // b*8+ch, total 16384
  int ch = id & 7;
  float A[55];
#pragma unroll
  for (int i = 0; i < 10; i++)
#pragma unroll
    for (int n = i; n < 10; n++) A[TIX(i, n)] = Sin[(i * 10 + n) * NE + id];
  float V[100];
  jacobi10(A, V);
  float f[10];
#pragma unroll
  for (int r = 0; r < 10; r++) f[r] = __logf(fmaxf(A[TIX(r, r)], EPSV));
  float acc[10];
#pragma unroll
  for (int c2 = 0; c2 < 10; c2++) acc[c2] = 0.f;
  const float* wbase = Wc + ch * 1000;     // row (ch*100 + i*10 + n), 10 cols
#pragma unroll
  for (int i = 0; i < 10; i++) {
    float wv[10];
#pragma unroll
    for (int r = 0; r < 10; r++) wv[r] = V[i * 10 + r] * f[r];
#pragma unroll
    for (int n = 0; n < 10; n++) {
      float lv = 0.f;
#pragma unroll
      for (int r = 0; r < 10; r++) lv = fmaf(wv[r], V[n * 10 + r], lv);
      const float* wrow = wbase + (i * 10 + n) * 10;
#pragma unroll
      for (int h = 0; h < 5; h++) {
        float2 wc2 = *(const float2*)(wrow + 2 * h);
        acc[2 * h]     = fmaf(lv, wc2.x, acc[2 * h]);
        acc[2 * h + 1] = fmaf(lv, wc2.y, acc[2 * h + 1]);
      }
    }
  }
  // reduce over the 8 channel lanes (lanes id&7 within each group of 8)
#pragma unroll
  for (int mk = 1; mk < 8; mk <<= 1) {
#pragma unroll
    for (int c2 = 0; c2 < 10; c2++) acc[c2] += __shfl_xor(acc[c2], mk, 8);
  }
  if (ch == 0) {
    int b = id >> 3;
#pragma unroll
    for (int c2 = 0; c2 < 10; c2++) out[b * 10 + c2] = acc[c2] + bcv[c2];
  }
}

// ---------------------------------------------------------------- launch
extern "C" void kernel_launch(void* const* d_in, const int* in_sizes, int n_in,
                              void* d_out, int out_size, void* d_ws, size_t ws_size,
                              hipStream_t stream) {
  const float* x      = (const float*)d_in[0];
  const float* Wst    = (const float*)d_in[1];
  const float* Wop0   = (const float*)d_in[2];
  const float* Wop1   = (const float*)d_in[3];
  const float* Wop2   = (const float*)d_in[4];
  const float* alphas = (const float*)d_in[5];
  const float* Wcls   = (const float*)d_in[6];
  const float* bcls   = (const float*)d_in[7];
  float* out = (float*)d_out;

  // workspace layout (floats): Sa(2048*800) | Sb(2048*800) | cand(55*12*2048*4)
  float* ws   = (float*)d_ws;
  float* Sa   = ws;
  float* Sb   = Sa + (size_t)NB * 800;
  float* cand = Sb + (size_t)NB * 800;

  k_cov_stem<<<NB, 256, 0, stream>>>(x, Wst, Sa);

  // cell 0: S (B,1,20,20) -> (B,2,10,10)   (DIN=20: split cand/logm path)
  k_cand20<<<NB, 256, 0, stream>>>(Sa, Wop0, cand, NB);
  k_logm<<<(12 * NB) / 256, 256, 0, stream>>>(cand, 12 * NB);
  k_expm<NB, 1><<<(2 * NB) / 64, 64, 0, stream>>>(cand, alphas, 0, Sb);

  // cell 1: (B,2,10,10) -> (B,4,10,10)   (fused cand+logm, elem-major S)
  k_candlogm<NB * 2><<<(12 * NB * 2) / 256, 256, 0, stream>>>(Sb, Wop1, cand);
  k_expm<NB * 2, 2><<<(4 * NB) / 64, 64, 0, stream>>>(cand, alphas, 1, Sa);

  // cell 2: (B,4,10,10) -> (B,8,10,10)
  k_candlogm<NB * 4><<<(12 * NB * 4) / 256, 256, 0, stream>>>(Sa, Wop2, cand);
  k_expm<NB * 4, 4><<<(8 * NB) / 64, 64, 0, stream>>>(cand, alphas, 2, Sb);

  // final logm + classifier (fused)
  k_final<<<(8 * NB) / 64, 64, 0, stream>>>(Sb, Wcls, bcls, out);
}

// Round 10
// 470.163 us; speedup vs baseline: 4.1466x; 3.9043x over previous
//
#include <hip/hip_runtime.h>
#include <math.h>

// Problem constants
#define WIN   20
#define NWIN  399          // (4000-20)/10+1
#define NCH   2
#define TLEN  4000
#define NFR   798          // NCH*NWIN
#define KOPS  6
#define NB    2048
#define EPSV  1e-6f
#define RIDGE 1e-3f

// packed upper triangle index for 10x10, i<=j
#define TIX(i,j) ((i)*10 - (i)*((i)+1)/2 + (j))

// fast hardware transcendentals (~1e-7 rel err; output tolerance is 2.3e-2)
__device__ __forceinline__ float frcp(float x){float r;asm("v_rcp_f32 %0, %1":"=v"(r):"v"(x));return r;}
__device__ __forceinline__ float frsq(float x){float r;asm("v_rsq_f32 %0, %1":"=v"(r):"v"(x));return r;}
__device__ __forceinline__ float fsqr(float x){float r;asm("v_sqrt_f32 %0, %1":"=v"(r):"v"(x));return r;}

// ---------------------------------------------------------------- Jacobi 10x10
// Sequential cyclic Jacobi (round-7 proven config: VGPR 184, zero spill).
// DO NOT batch angles across rotations (rounds 8/9: tournament ILP batching
// spilled — VGPR 216-228 + ~26MB scratch writes + VALUBusy 11-19%, 4x slower).
// DO NOT use 512-thread blocks or min-occupancy hints (rounds 2/5/6: 128-VGPR
// cap -> full spill). Only 64/256-thread blocks, no hints.
// A: packed upper triangle (55), V: row-major 10x10 (100). On exit diag(A)=evals,
// columns of V are eigenvectors: A_orig = V diag V^T.
__device__ __forceinline__ void jacobi10(float* A, float* V) {
#pragma unroll
  for (int i = 0; i < 100; i++) V[i] = 0.f;
#pragma unroll
  for (int i = 0; i < 10; i++) V[i * 11] = 1.f;

  for (int sweep = 0; sweep < 7; ++sweep) {
    float off = 0.f, dia = 0.f;
#pragma unroll
    for (int p = 0; p < 10; p++) {
      float d = A[TIX(p, p)];
      dia = fmaf(d, d, dia);
#pragma unroll
      for (int q = p + 1; q < 10; q++) { float o = A[TIX(p, q)]; off = fmaf(o, o, off); }
    }
    float fro2 = dia + 2.f * off;
    if (__ballot(off > 1e-11f * fro2) == 0ull) break;
    float skipthr = 1e-12f * fro2;

#pragma unroll
    for (int p = 0; p < 10; p++) {
#pragma unroll
      for (int q = p + 1; q < 10; q++) {
        float apq = A[TIX(p, q)];
        // skip rotation if every lane's pivot is negligible (late sweeps)
        if (__ballot(apq * apq > skipthr) == 0ull) continue;
        float app = A[TIX(p, p)];
        float aqq = A[TIX(q, q)];
        bool rot = fabsf(apq) > 1e-30f;
        float theta = (aqq - app) * frcp(rot ? 2.f * apq : 1.f);
        float t = copysignf(frcp(fabsf(theta) + fsqr(fmaf(theta, theta, 1.f))), theta);
        t = rot ? t : 0.f;                       // t=0 -> c=1, s=0: identity rotation
        float c = frsq(fmaf(t, t, 1.f));
        float s = t * c;
#pragma unroll
        for (int j = 0; j < 10; j++) {
          if (j == p || j == q) continue;
          const int jp = (j < p) ? TIX(j, p) : TIX(p, j);
          const int jq = (j < q) ? TIX(j, q) : TIX(q, j);
          float ajp = A[jp], ajq = A[jq];
          A[jp] = fmaf(c, ajp, -s * ajq);
          A[jq] = fmaf(s, ajp, c * ajq);
        }
        A[TIX(p, p)] = fmaf(-t, apq, A[TIX(p, p)]);
        A[TIX(q, q)] = fmaf(t, apq, A[TIX(q, q)]);
        A[TIX(p, q)] = 0.0f;
#pragma unroll
        for (int i = 0; i < 10; i++) {
          float vip = V[i * 10 + p], viq = V[i * 10 + q];
          V[i * 10 + p] = fmaf(c, vip, -s * viq);
          V[i * 10 + q] = fmaf(s, vip, c * viq);
        }
      }
    }
  }
}

// ---------------------------------------------------------------- cov + stem
// hop-block decomposition: frame w = [b_w ; b_{w+1}] (10-blocks), w=0..398 per channel.
// C00 = T - b399 b399^T, C11 = T - b0 b0^T, C01 = Q, with
// T = sum_{i=0..399} b_i b_i^T, Q = sum_{i=0..398} b_i b_{i+1}^T (per channel).
__global__ __launch_bounds__(256) void k_cov_stem(const float* __restrict__ x,
                                                  const float* __restrict__ Wst,
                                                  float* __restrict__ Sout) {
  __shared__ float xl[NCH * TLEN];
  __shared__ float pT[2][NCH][100];   // [seg][ch][d*10+e]
  __shared__ float pQ[2][NCH][100];
  __shared__ float bsum[NCH][10];
  __shared__ float b0v[NCH][10];
  __shared__ float b399v[NCH][10];
  __shared__ float cov[400];
  __shared__ float wst[400];
  __shared__ float tmp[400];
  int b = blockIdx.x, tid = threadIdx.x;
  const float4* xg = (const float4*)(x + (size_t)b * NCH * TLEN);
  float4* xl4 = (float4*)xl;
  for (int i = tid; i < NCH * TLEN / 4; i += 256) xl4[i] = xg[i];
  for (int i = tid; i < 400; i += 256) wst[i] = Wst[i];
  __syncthreads();

  if (tid < 200) {
    int grp = tid / 100;               // 0 = T, 1 = Q
    int c = (tid % 100) / 50;
    int r = tid % 50;
    int seg = r / 25, tile = r % 25;
    int d0 = (tile / 5) * 2, e0 = (tile % 5) * 2;
    const float* xc = xl + c * TLEN;
    int i0 = seg * 200;
    int i1 = grp ? ((seg == 1) ? 399 : 200) : (i0 + 200);
    int eoff = grp ? 10 : 0;
    float a00 = 0.f, a01 = 0.f, a10 = 0.f, a11 = 0.f;
    for (int i = i0; i < i1; i++) {
      float2 bd = *(const float2*)(xc + i * 10 + d0);
      float2 be = *(const float2*)(xc + i * 10 + eoff + e0);
      a00 = fmaf(bd.x, be.x, a00); a01 = fmaf(bd.x, be.y, a01);
      a10 = fmaf(bd.y, be.x, a10); a11 = fmaf(bd.y, be.y, a11);
    }
    float* dst = grp ? &pQ[seg][c][0] : &pT[seg][c][0];
    dst[d0 * 10 + e0] = a00;
    dst[d0 * 10 + e0 + 1] = a01;
    dst[(d0 + 1) * 10 + e0] = a10;
    dst[(d0 + 1) * 10 + e0 + 1] = a11;
  } else if (tid >= 200 && tid < 220) {
    int c = (tid - 200) / 10, d = (tid - 200) % 10;
    const float* xc = xl + c * TLEN;
    float s = 0.f;
    for (int i = 0; i < 400; i++) s += xc[i * 10 + d];
    bsum[c][d] = s;
    b0v[c][d] = xc[d];
    b399v[c][d] = xc[3990 + d];
  }
  __syncthreads();

  const float invN = 1.0f / (float)NFR;
  const float invN1 = 1.0f / (float)(NFR - 1);
  for (int o = tid; o < 400; o += 256) {
    int d = o / 20, e = o % 20;
    int dl = d % 10, el = e % 10;
    float s2;
    if (d < 10 && e < 10)
      s2 = (pT[0][0][dl * 10 + el] + pT[1][0][dl * 10 + el] - b399v[0][dl] * b399v[0][el]) +
           (pT[0][1][dl * 10 + el] + pT[1][1][dl * 10 + el] - b399v[1][dl] * b399v[1][el]);
    else if (d >= 10 && e >= 10)
      s2 = (pT[0][0][dl * 10 + el] + pT[1][0][dl * 10 + el] - b0v[0][dl] * b0v[0][el]) +
           (pT[0][1][dl * 10 + el] + pT[1][1][dl * 10 + el] - b0v[1][dl] * b0v[1][el]);
    else if (d < 10)
      s2 = pQ[0][0][dl * 10 + el] + pQ[1][0][dl * 10 + el] +
           pQ[0][1][dl * 10 + el] + pQ[1][1][dl * 10 + el];
    else
      s2 = pQ[0][0][el * 10 + dl] + pQ[1][0][el * 10 + dl] +
           pQ[0][1][el * 10 + dl] + pQ[1][1][el * 10 + dl];
    float md = (d < 10) ? (bsum[0][dl] - b399v[0][dl] + bsum[1][dl] - b399v[1][dl])
                        : (bsum[0][dl] - b0v[0][dl] + bsum[1][dl] - b0v[1][dl]);
    float me = (e < 10) ? (bsum[0][el] - b399v[0][el] + bsum[1][el] - b399v[1][el])
                        : (bsum[0][el] - b0v[0][el] + bsum[1][el] - b0v[1][el]);
    float v = (s2 - (float)NFR * (md * invN) * (me * invN)) * invN1;
    if (d == e) v += RIDGE;
    cov[o] = v;
  }
  __syncthreads();
  for (int o = tid; o < 400; o += 256) {
    int j = o / 20, l = o % 20;
    float acc = 0.f;
    for (int k2 = 0; k2 < 20; k2++) acc = fmaf(cov[j * 20 + k2], wst[k2 * 20 + l], acc);
    tmp[o] = acc;
  }
  __syncthreads();
  for (int o = tid; o < 400; o += 256) {
    int i = o / 20, l = o % 20;
    float acc = 0.f;
    for (int j = 0; j < 20; j++) acc = fmaf(wst[j * 20 + i], tmp[j * 20 + l], acc);
    if (i == l) acc += RIDGE;
    Sout[b * 400 + o] = acc;
  }
}

// ---------------------------------------------------------------- cand = W^T S W + ridge I (cell 0 only, DIN=20)
__global__ __launch_bounds__(256) void k_cand20(const float* __restrict__ Sin,
                                                const float* __restrict__ Wop,
                                                float* __restrict__ cand, int BC) {
  const int DIN = 20;
  __shared__ float Sl[DIN * DIN];
  __shared__ float Wl[12 * DIN * 10];
  __shared__ float Tl[12 * DIN * 10];
  int bc = blockIdx.x, tid = threadIdx.x;
  for (int i = tid; i < DIN * DIN; i += 256) Sl[i] = Sin[bc * DIN * DIN + i];
  for (int i = tid; i < 12 * DIN * 10; i += 256) Wl[i] = Wop[i];
  __syncthreads();
  for (int o = tid; o < 12 * DIN * 10; o += 256) {
    int mk = o / (DIN * 10);
    int r = o % (DIN * 10);
    int j = r / 10, n = r % 10;
    float acc = 0.f;
    for (int l = 0; l < DIN; l++) acc = fmaf(Sl[j * DIN + l], Wl[mk * DIN * 10 + l * 10 + n], acc);
    Tl[o] = acc;
  }
  __syncthreads();
  int NM = 12 * BC;
  for (int o = tid; o < 12 * 55; o += 256) {
    int mk = o / 55, t = o % 55;
    int t0 = t, i = 0;
    while (t0 >= 10 - i) { t0 -= 10 - i; i++; }
    int n = i + t0;
    float acc = 0.f;
    for (int j = 0; j < DIN; j++)
      acc = fmaf(Wl[mk * DIN * 10 + j * 10 + i], Tl[mk * DIN * 10 + j * 10 + n], acc);
    if (i == n) acc += RIDGE;
    cand[t * NM + mk * BC + bc] = acc;
  }
}

// ---------------------------------------------------------------- shared logm epilogue
__device__ __forceinline__ void logm_epilogue(float* A, float* V,
                                              float* __restrict__ cand, int NM, int mat) {
  float f[10];
#pragma unroll
  for (int r = 0; r < 10; r++) f[r] = __logf(fmaxf(A[TIX(r, r)], EPSV));
#pragma unroll
  for (int i = 0; i < 10; i++) {
    float w[10];
#pragma unroll
    for (int r = 0; r < 10; r++) w[r] = V[i * 10 + r] * f[r];
#pragma unroll
    for (int n = i; n < 10; n++) {
      float acc = 0.f;
#pragma unroll
      for (int r = 0; r < 10; r++) acc = fmaf(w[r], V[n * 10 + r], acc);
      cand[TIX(i, n) * NM + mat] = acc;
    }
  }
}

// ---------------------------------------------------------------- logm from cand buffer (cell 0)
__global__ __launch_bounds__(256) void k_logm(float* __restrict__ cand, int NM) {
  int mat = blockIdx.x * 256 + threadIdx.x;   // NM is a multiple of 256
  float A[55];
#pragma unroll
  for (int t = 0; t < 55; t++) A[t] = cand[t * NM + mat];
  float V[100];
  jacobi10(A, V);
  logm_epilogue(A, V, cand, NM, mat);
}

// ---------------------------------------------------------------- fused cand+logm (cells 1,2; DIN=10)
// S is element-major [e][BC] (written by k_expm) -> fully coalesced reads.
template <int BC>
__global__ __launch_bounds__(256) void k_candlogm(const float* __restrict__ Sin,
                                                  const float* __restrict__ Wop,
                                                  float* __restrict__ cand) {
  __shared__ float Wl[1200];
  int tid = threadIdx.x;
  for (int i = tid; i < 1200; i += 256) Wl[i] = Wop[i];
  __syncthreads();
  const int NM = 12 * BC;
  int mat = blockIdx.x * 256 + tid;
  int mk = mat / BC, bc = mat % BC;      // 256 | BC, so mk uniform per block
  const float* Wm = Wl + mk * 100;
  const float* Sb = Sin + bc;            // elem-major: S[e*BC + bc]

  float U[100];
#pragma unroll
  for (int i = 0; i < 100; i++) U[i] = 0.f;
#pragma unroll
  for (int j = 0; j < 10; j++) {
    float sr[10];
#pragma unroll
    for (int l = 0; l < 10; l++) sr[l] = Sb[(j * 10 + l) * BC];
    float wr[10];
#pragma unroll
    for (int i = 0; i < 10; i++) wr[i] = Wm[j * 10 + i];
#pragma unroll
    for (int i = 0; i < 10; i++)
#pragma unroll
      for (int l = 0; l < 10; l++) U[i * 10 + l] = fmaf(wr[i], sr[l], U[i * 10 + l]);
  }
  float A[55];
#pragma unroll
  for (int t = 0; t < 55; t++) A[t] = 0.f;
#pragma unroll
  for (int i = 0; i < 10; i++) A[TIX(i, i)] = RIDGE;
#pragma unroll
  for (int l = 0; l < 10; l++) {
    float wr[10];
#pragma unroll
    for (int n = 0; n < 10; n++) wr[n] = Wm[l * 10 + n];
#pragma unroll
    for (int i = 0; i < 10; i++) {
      float u = U[i * 10 + l];
#pragma unroll
      for (int n = i; n < 10; n++) A[TIX(i, n)] = fmaf(u, wr[n], A[TIX(i, n)]);
    }
  }
  float V[100];
  jacobi10(A, V);
  logm_epilogue(A, V, cand, NM, mat);
}

// ---------------------------------------------------------------- sparsemax (per-thread, K=6)
__device__ __forceinline__ void sparsemax6(const float* __restrict__ a, int row, float* w) {
  float z[KOPS], zs[KOPS];
#pragma unroll
  for (int i = 0; i < KOPS; i++) { z[i] = a[row * KOPS + i]; zs[i] = z[i]; }
#pragma unroll
  for (int i = 0; i < KOPS; i++)
#pragma unroll
    for (int j = i + 1; j < KOPS; j++)
      if (zs[j] > zs[i]) { float tm = zs[i]; zs[i] = zs[j]; zs[j] = tm; }
  float acc = 0.f, zcp = 1.f; float cnt = 1.f;
#pragma unroll
  for (int i = 0; i < KOPS; i++) {
    acc += zs[i];
    if (1.0f + (float)(i + 1) * zs[i] > acc) { cnt = (float)(i + 1); zcp = acc; }
  }
  float tau = (zcp - 1.0f) / cnt;
#pragma unroll
  for (int i = 0; i < KOPS; i++) w[i] = fmaxf(z[i] - tau, 0.0f);
}

// ---------------------------------------------------------------- expm of weighted sum -> new S
// Output element-major [e][2*BC] -> fully coalesced stores, coalesced reads downstream.
template <int BC, int C>
__global__ __launch_bounds__(64) void k_expm(const float* __restrict__ L,
                                             const float* __restrict__ alphas, int row,
                                             float* __restrict__ Sout) {
  const int NM = 12 * BC;
  const int NE = 2 * BC;
  int id = blockIdx.x * 64 + threadIdx.x;  // id = m*BC + bc; 2*BC is a multiple of 64
  int m = id / BC;
  int bc = id % BC;
  float w[KOPS];
  sparsemax6(alphas, row, w);
  float A[55];
#pragma unroll
  for (int t = 0; t < 55; t++) {
    float acc = 0.f;
#pragma unroll
    for (int k2 = 0; k2 < KOPS; k2++) acc = fmaf(w[k2], L[t * NM + (m * KOPS + k2) * BC + bc], acc);
    A[t] = acc;
  }
  float V[100];
  jacobi10(A, V);
  float f[10];
#pragma unroll
  for (int r = 0; r < 10; r++) f[r] = __expf(A[TIX(r, r)]);
  int b = bc / C, c = bc % C;
  int idm = b * 2 * C + m * C + c;         // next stage's bc index
  float* out = Sout + idm;
#pragma unroll
  for (int i = 0; i < 10; i++) {
    float wv[10];
#pragma unroll
    for (int r = 0; r < 10; r++) wv[r] = V[i * 10 + r] * f[r];
#pragma unroll
    for (int n = i; n < 10; n++) {
      float acc = 0.f;
#pragma unroll
      for (int r = 0; r < 10; r++) acc = fmaf(wv[r], V[n * 10 + r], acc);
      out[(i * 10 + n) * NE] = acc;
      if (n != i) out[(n * 10 + i) * NE] = acc;
    }
  }
}

// ---------------------------------------------------------------- final logm + classifier (fused)
// S elem-major [e][16384]. Each thread: logm of one (b,ch) matrix, classifier
// partials acc[10], shfl-reduce over the 8 ch lanes, lane ch==0 stores.
__global__ __launch_bounds__(64) void k_final(const float* __restrict__ Sin,
                                              const float* __restrict__ Wc,
                                              const float* __restrict__ bcv,
                                              float* __restrict__ out) {
  const int NE = 8 * NB;
  int id = blockIdx.x * 64 + threadIdx.x;  // b*8+ch, total 16384
  int ch = id & 7;
  float A[55];
#pragma unroll
  for (int i = 0; i < 10; i++)
#pragma unroll
    for (int n = i; n < 10; n++) A[TIX(i, n)] = Sin[(i * 10 + n) * NE + id];
  float V[100];
  jacobi10(A, V);
  float f[10];
#pragma unroll
  for (int r = 0; r < 10; r++) f[r] = __logf(fmaxf(A[TIX(r, r)], EPSV));
  float acc[10];
#pragma unroll
  for (int c2 = 0; c2 < 10; c2++) acc[c2] = 0.f;
  const float* wbase = Wc + ch * 1000;     // row (ch*100 + i*10 + n), 10 cols
#pragma unroll
  for (int i = 0; i < 10; i++) {
    float wv[10];
#pragma unroll
    for (int r = 0; r < 10; r++) wv[r] = V[i * 10 + r] * f[r];
#pragma unroll
    for (int n = 0; n < 10; n++) {
      float lv = 0.f;
#pragma unroll
      for (int r = 0; r < 10; r++) lv = fmaf(wv[r], V[n * 10 + r], lv);
      const float* wrow = wbase + (i * 10 + n) * 10;
#pragma unroll
      for (int h = 0; h < 5; h++) {
        float2 wc2 = *(const float2*)(wrow + 2 * h);
        acc[2 * h]     = fmaf(lv, wc2.x, acc[2 * h]);
        acc[2 * h + 1] = fmaf(lv, wc2.y, acc[2 * h + 1]);
      }
    }
  }
  // reduce over the 8 channel lanes (lanes id&7 within each group of 8)
#pragma unroll
  for (int mk = 1; mk < 8; mk <<= 1) {
#pragma unroll
    for (int c2 = 0; c2 < 10; c2++) acc[c2] += __shfl_xor(acc[c2], mk, 8);
  }
  if (ch == 0) {
    int b = id >> 3;
#pragma unroll
    for (int c2 = 0; c2 < 10; c2++) out[b * 10 + c2] = acc[c2] + bcv[c2];
  }
}

// ---------------------------------------------------------------- launch
extern "C" void kernel_launch(void* const* d_in, const int* in_sizes, int n_in,
                              void* d_out, int out_size, void* d_ws, size_t ws_size,
                              hipStream_t stream) {
  const float* x      = (const float*)d_in[0];
  const float* Wst    = (const float*)d_in[1];
  const float* Wop0   = (const float*)d_in[2];
  const float* Wop1   = (const float*)d_in[3];
  const float* Wop2   = (const float*)d_in[4];
  const float* alphas = (const float*)d_in[5];
  const float* Wcls   = (const float*)d_in[6];
  const float* bcls   = (const float*)d_in[7];
  float* out = (float*)d_out;

  // workspace layout (floats): Sa(2048*800) | Sb(2048*800) | cand(55*12*2048*4)
  float* ws   = (float*)d_ws;
  float* Sa   = ws;
  float* Sb   = Sa + (size_t)NB * 800;
  float* cand = Sb + (size_t)NB * 800;

  k_cov_stem<<<NB, 256, 0, stream>>>(x, Wst, Sa);

  // cell 0: S (B,1,20,20) -> (B,2,10,10)   (DIN=20: split cand/logm path)
  k_cand20<<<NB, 256, 0, stream>>>(Sa, Wop0, cand, NB);
  k_logm<<<(12 * NB) / 256, 256, 0, stream>>>(cand, 12 * NB);
  k_expm<NB, 1><<<(2 * NB) / 64, 64, 0, stream>>>(cand, alphas, 0, Sb);

  // cell 1: (B,2,10,10) -> (B,4,10,10)   (fused cand+logm, elem-major S)
  k_candlogm<NB * 2><<<(12 * NB * 2) / 256, 256, 0, stream>>>(Sb, Wop1, cand);
  k_expm<NB * 2, 2><<<(4 * NB) / 64, 64, 0, stream>>>(cand, alphas, 1, Sa);

  // cell 2: (B,4,10,10) -> (B,8,10,10)
  k_candlogm<NB * 4><<<(12 * NB * 4) / 256, 256, 0, stream>>>(Sa, Wop2, cand);
  k_expm<NB * 4, 4><<<(8 * NB) / 64, 64, 0, stream>>>(cand, alphas, 2, Sb);

  // final logm + classifier (fused)
  k_final<<<(8 * NB) / 64, 64, 0, stream>>>(Sb, Wcls, bcls, out);
}